// Round 17
// baseline (228.579 us; speedup 1.0000x reference)
//
#include <hip/hip_runtime.h>

constexpr int CN = 4;          // batch
constexpr int CC = 64;         // channels per window
constexpr int CH = 72, CW = 72;
constexpr int HW = CH * CW;    // 5184
constexpr int NPOS = CN * HW;  // 20736 tokens per window
constexpr long TOKF = 3L * NPOS * 64;  // elems in one [3][NPOS][64] array
constexpr long HPAD = 4096;            // tail pad (halves) for OOB-safe reads

typedef _Float16 h4 __attribute__((ext_vector_type(4)));
typedef _Float16 h8 __attribute__((ext_vector_type(8)));
typedef float f4 __attribute__((ext_vector_type(4)));

// f16 [row][64] arrays: 8 granules of 8 f16 per row; swizzle granule by row&7.
__device__ __forceinline__ int fidx(int row, int g, int off) {
  return (row << 6) + ((g ^ (row & 7)) << 3) + off;
}
// f16 [row][192] arrays: 24 granules; swizzle low 3 bits of granule by row&7.
__device__ __forceinline__ int f192(int row, int g) {
  return row * 192 + (((g & 24) | ((g ^ row) & 7)) << 3);
}

// ---------------------------------------------------------------------------
// Kernel 1: expand conv (3 windows, output-split x4 for occupancy) +
// weight transpose/split, one launch.
// ---------------------------------------------------------------------------
template <int WW, int SS>
__device__ __forceinline__ void expand_body(const float* __restrict__ x,
                                            const float* __restrict__ w64,
                                            const float* __restrict__ b64,
                                            float* __restrict__ out, int pg,
                                            int og0) {
  int n = pg / HW;
  int pos = pg - n * HW;
  int h = pos / CW, wcol = pos % CW;

  float xv[64];
  const float* xp = x + (long)n * CC * HW + pos;
#pragma unroll
  for (int c = 0; c < 64; ++c) xv[c] = xp[c * HW];

  int wr = h / SS, kx = h % SS, wcq = wcol / SS, ky = wcol % SS;
  int j = kx * (SS * WW * WW) + ky * (WW * WW) + wr * WW + wcq;
  float* op = out + ((long)n * HW + j) * 64;

#pragma unroll
  for (int og = og0; og < og0 + 4; ++og) {
    float t0[4];
#pragma unroll
    for (int i = 0; i < 4; ++i) {
      int o = og * 4 + i;
      float acc = b64[o];
      const float* wp = w64 + o * 64;
#pragma unroll
      for (int cg = 0; cg < 16; ++cg) {
        float4 w4 = *(const float4*)(wp + 4 * cg);
        acc = fmaf(xv[4 * cg + 0], w4.x, acc);
        acc = fmaf(xv[4 * cg + 1], w4.y, acc);
        acc = fmaf(xv[4 * cg + 2], w4.z, acc);
        acc = fmaf(xv[4 * cg + 3], w4.w, acc);
      }
      t0[i] = acc;
    }
    *(float4*)(op + og * 4) = make_float4(t0[0], t0[1], t0[2], t0[3]);
  }
}

__global__ __launch_bounds__(256) void k_prep(
    const float* __restrict__ x, const float* __restrict__ exp_w,
    const float* __restrict__ exp_b, const float* __restrict__ wq,
    const float* __restrict__ wk, const float* __restrict__ wv,
    const float* __restrict__ res_w, const float* __restrict__ fus_w,
    float* __restrict__ ex, _Float16* __restrict__ wTh,
    _Float16* __restrict__ wTl, _Float16* __restrict__ rwh,
    _Float16* __restrict__ rwl, _Float16* __restrict__ fwh,
    _Float16* __restrict__ fwl) {
  int b = blockIdx.x;
  if (b >= 972) {  // weight transpose + hi/lo split part
    int i = (b - 972) * 256 + threadIdx.x;  // [0, 28672)
    float v;
    _Float16 *dh, *dl;
    int off;
    if (i < 12288) {
      int m = i >> 12;
      int r = i & 4095;
      int cp = r >> 6, c = r & 63;
      const float* src = (m == 0) ? wq : ((m == 1) ? wk : wv);
      v = src[c * 64 + cp];
      dh = wTh; dl = wTl; off = i;
    } else if (i < 24576) {
      off = i - 12288;
      v = res_w[off];
      dh = rwh; dl = rwl;
    } else {
      off = i - 24576;
      v = fus_w[off];
      dh = fwh; dl = fwl;
    }
    _Float16 h = (_Float16)v;
    dh[off] = h;
    dl[off] = (_Float16)(v - (float)h);
    return;
  }
  int wi = b / 324;                // window
  int b2 = b - wi * 324;
  int og0 = (b2 / 81) * 4;         // output-group quarter
  int pg = (b2 % 81) * 256 + threadIdx.x;  // [0, NPOS)
  if (wi == 0)
    expand_body<2, 36>(x, exp_w, exp_b, ex, pg, og0);
  else if (wi == 1)
    expand_body<4, 18>(x, exp_w + 4096, exp_b + 64, ex + (long)NPOS * 64, pg,
                       og0);
  else
    expand_body<6, 12>(x, exp_w + 8192, exp_b + 128, ex + 2L * NPOS * 64, pg,
                       og0);
}

// ---------------------------------------------------------------------------
// Kernel 2: q/k/v projections as MFMA fp16 hi/lo GEMM (3-term, fp32-equiv).
// ---------------------------------------------------------------------------
__global__ __launch_bounds__(256) void k_qkv(
    const float* __restrict__ ex, const _Float16* __restrict__ wTh,
    const _Float16* __restrict__ wTl, _Float16* __restrict__ qh,
    _Float16* __restrict__ ql, _Float16* __restrict__ kh,
    _Float16* __restrict__ kl, _Float16* __restrict__ vth,
    _Float16* __restrict__ vtl) {
  __shared__ __align__(16) _Float16 Wh[12288], Wl[12288];  // 192x64 swizzled
  __shared__ __align__(16) float Cb[4096];  // bounce; overlays E staging
  _Float16* Eh = (_Float16*)Cb;             // [64][64] halves
  _Float16* El = (_Float16*)Cb + 4096;

  const int tid = threadIdx.x;
  const long tok0 = (long)blockIdx.x * 64;
  const int lane = tid & 63, w = tid >> 6;
  const int lw = lane & 15, lg = lane >> 4;

  // ---- stage E (split) ----
  {
    int srow = tid >> 2, sfq = tid & 3;
#pragma unroll
    for (int p = 0; p < 4; ++p) {
      int c0 = (4 * p + sfq) * 4;
      float4 v = *(const float4*)(ex + (tok0 + srow) * 64 + c0);
      h4 hh = {(_Float16)v.x, (_Float16)v.y, (_Float16)v.z, (_Float16)v.w};
      h4 ll = {(_Float16)(v.x - (float)hh[0]), (_Float16)(v.y - (float)hh[1]),
               (_Float16)(v.z - (float)hh[2]), (_Float16)(v.w - (float)hh[3])};
      *(h4*)&Eh[fidx(srow, c0 >> 3, c0 & 7)] = hh;
      *(h4*)&El[fidx(srow, c0 >> 3, c0 & 7)] = ll;
    }
  }
  // ---- stage W (straight split copies) ----
#pragma unroll
  for (int it = 0; it < 6; ++it) {
    int idx = it * 256 + tid;  // [0,1536) h8 index
    int row = idx >> 3, gr = idx & 7;
    *(h8*)&Wh[fidx(row, gr, 0)] = *(const h8*)(wTh + idx * 8);
    *(h8*)&Wl[fidx(row, gr, 0)] = *(const h8*)(wTl + idx * 8);
  }
  __syncthreads();

  // ---- A-fragments (E rows) to registers, then free the E region ----
  h8 eh[2], el[2];
#pragma unroll
  for (int s = 0; s < 2; ++s) {
    eh[s] = *(const h8*)&Eh[fidx(w * 16 + lw, s * 4 + lg, 0)];
    el[s] = *(const h8*)&El[fidx(w * 16 + lw, s * 4 + lg, 0)];
  }
  __syncthreads();

  const float SC = 0.125f * 1.4426950408889634f;
#pragma unroll 1
  for (int p = 0; p < 3; ++p) {
#pragma unroll
    for (int ot = 0; ot < 4; ++ot) {
      f4 acc = (f4){0.f, 0.f, 0.f, 0.f};
#pragma unroll
      for (int s = 0; s < 2; ++s) {
        h8 bh = *(const h8*)&Wh[fidx(p * 64 + ot * 16 + lw, s * 4 + lg, 0)];
        h8 bl = *(const h8*)&Wl[fidx(p * 64 + ot * 16 + lw, s * 4 + lg, 0)];
        acc = __builtin_amdgcn_mfma_f32_16x16x32_f16(eh[s], bh, acc, 0, 0, 0);
        acc = __builtin_amdgcn_mfma_f32_16x16x32_f16(el[s], bh, acc, 0, 0, 0);
        acc = __builtin_amdgcn_mfma_f32_16x16x32_f16(eh[s], bl, acc, 0, 0, 0);
      }
#pragma unroll
      for (int r = 0; r < 4; ++r) {
        int row = w * 16 + 4 * lg + r;
        int col = ot * 16 + lw;
        Cb[(row << 6) + ((((col >> 2) ^ (row & 15))) << 2) + (col & 3)] =
            acc[r];
      }
    }
    __syncthreads();

    if (p < 2) {
      int tokl = tid >> 2, off = (tid & 3) * 16;
      float vals[16];
#pragma unroll
      for (int j = 0; j < 4; ++j) {
        int slot = (off >> 2) + j;
        f4 v = *(const f4*)&Cb[(tokl << 6) + (((slot ^ (tokl & 15))) << 2)];
        vals[4 * j + 0] = v[0]; vals[4 * j + 1] = v[1];
        vals[4 * j + 2] = v[2]; vals[4 * j + 3] = v[3];
      }
      float sc = (p == 0) ? SC : 1.0f;
      _Float16* dh = (p == 0 ? qh : kh) + (tok0 + tokl) * 64 + off;
      _Float16* dl = (p == 0 ? ql : kl) + (tok0 + tokl) * 64 + off;
      h8 hh0, hh1, ll0, ll1;
#pragma unroll
      for (int j = 0; j < 8; ++j) {
        float x0 = vals[j] * sc;
        _Float16 h = (_Float16)x0;
        hh0[j] = h;
        ll0[j] = (_Float16)(x0 - (float)h);
        float x1 = vals[8 + j] * sc;
        _Float16 h1 = (_Float16)x1;
        hh1[j] = h1;
        ll1[j] = (_Float16)(x1 - (float)h1);
      }
      *(h8*)dh = hh0; *(h8*)(dh + 8) = hh1;
      *(h8*)dl = ll0; *(h8*)(dl + 8) = ll1;
    } else {
      int ch0 = (tid & 15) * 4, tokl0 = (tid >> 4) * 4;
      float tv[4][4];
#pragma unroll
      for (int r = 0; r < 4; ++r) {
        int row = tokl0 + r;
        int slot = (ch0 >> 2) ^ (row & 15);
        f4 v = *(const f4*)&Cb[(row << 6) + (slot << 2)];
        tv[r][0] = v[0]; tv[r][1] = v[1]; tv[r][2] = v[2]; tv[r][3] = v[3];
      }
      long tokg = tok0 + tokl0;
      int wi = (int)(tokg / NPOS);
      long tl = tokg - (long)wi * NPOS;
      int L = (wi == 0) ? 1296 : ((wi == 1) ? 324 : 144);
      int g = (int)(tl / L);
      int key0 = (int)(tl - (long)g * L);
      long base = (long)wi * NPOS * 64 + (long)g * 64 * L + key0;
#pragma unroll
      for (int i = 0; i < 4; ++i) {
        h4 hh, ll;
#pragma unroll
        for (int r = 0; r < 4; ++r) {
          _Float16 h = (_Float16)tv[r][i];
          hh[r] = h;
          ll[r] = (_Float16)(tv[r][i] - (float)h);
        }
        *(h4*)&vth[base + (long)(ch0 + i) * L] = hh;
        *(h4*)&vtl[base + (long)(ch0 + i) * L] = ll;
      }
    }
    __syncthreads();
  }
}

// ---------------------------------------------------------------------------
// Kernel 3: merged MFMA attention, K/V fragments loaded DIRECTLY from global
// (group K/V is XCD-pinned L2-resident; LDS staging was the bottleneck).
// LDS holds only P (wave-private) -> NO barriers in the chunk loop.
// ---------------------------------------------------------------------------
__global__ __launch_bounds__(256) void k_attn(
    const _Float16* __restrict__ qg, const _Float16* __restrict__ qgl,
    const _Float16* __restrict__ kg, const _Float16* __restrict__ kgl,
    const _Float16* __restrict__ vg, const _Float16* __restrict__ vgl,
    float* __restrict__ og_) {
  __shared__ __align__(16) _Float16 Ph[4096], Pl[4096];  // P [q=64][key=64]

  const int tid = threadIdx.x;
  int b = blockIdx.x;
  int L, g, qt, NCH;
  long tokbase, vbase;
  if (b < 336) {          // w1: 16 groups x 21 tiles; g = b mod 16 (XCD-pin)
    L = 1296; NCH = 21; g = b & 15; qt = b >> 4;
    tokbase = (long)g * 1296;
    vbase = (long)g * 1296 * 64;
  } else if (b < 720) {   // w2: 64 groups x 6 tiles; g = t mod 64
    int t = b - 336;
    L = 324; NCH = 6; g = t & 63; qt = t >> 6;
    tokbase = (long)NPOS + (long)g * 324;
    vbase = (long)NPOS * 64 + (long)g * 324 * 64;
  } else {                // w3: 144 groups x 3 tiles; g = t mod 144
    int t = b - 720;
    L = 144; NCH = 3; g = t % 144; qt = t / 144;
    tokbase = 2L * NPOS + (long)g * 144;
    vbase = 2L * NPOS * 64 + (long)g * 144 * 64;
  }

  const int lane = tid & 63, w = tid >> 6;
  const int lw = lane & 15, lg = lane >> 4;
  const int w16 = w * 16;

  // ---- Q fragments straight to registers (loop-invariant; pad-safe) ----
  h8 qfh[2], qfl[2];
  {
    long qb = (tokbase + (long)qt * 64 + w16 + lw) * 64;
#pragma unroll
    for (int s = 0; s < 2; ++s) {
      qfh[s] = *(const h8*)(qg + qb + (s * 4 + lg) * 8);
      qfl[s] = *(const h8*)(qgl + qb + (s * 4 + lg) * 8);
    }
  }

  float m_s = -1e30f, l_s = 0.f;
  f4 oa[4];
#pragma unroll
  for (int i = 0; i < 4; ++i) oa[i] = (f4){0.f, 0.f, 0.f, 0.f};

  // per-lane fragment bases (loop-invariant parts)
  const long kfb = (tokbase + lw) * 64 + lg * 8;      // +kt*1024 +slab*32; ch: +=4096
  const long vfb = vbase + (long)lw * L + lg * 8;     // +ct*16*L +slab*32; ch: +=64
  const long vctL = (long)16 * L;

  for (int ch = 0; ch < NCH; ++ch) {
    const long kc = kfb + ((long)ch << 12);
    const long vc = vfb + ch * 64;

    // ---- S^T = K * Q^T (K fragments from global/L2) ----
    f4 sa[4];
#pragma unroll
    for (int kt = 0; kt < 4; ++kt) sa[kt] = (f4){0.f, 0.f, 0.f, 0.f};
#pragma unroll
    for (int slab = 0; slab < 2; ++slab) {
      h8 qbh = qfh[slab];
      h8 qbl = qfl[slab];
#pragma unroll
      for (int kt = 0; kt < 4; ++kt) {
        long ka = kc + kt * 1024 + slab * 32;
        h8 ah = *(const h8*)(kg + ka);
        h8 al = *(const h8*)(kgl + ka);
        sa[kt] = __builtin_amdgcn_mfma_f32_16x16x32_f16(ah, qbh, sa[kt], 0, 0, 0);
        sa[kt] = __builtin_amdgcn_mfma_f32_16x16x32_f16(al, qbh, sa[kt], 0, 0, 0);
        sa[kt] = __builtin_amdgcn_mfma_f32_16x16x32_f16(ah, qbl, sa[kt], 0, 0, 0);
      }
    }

    // ---- online softmax (exp2 domain, defer-max THR=8) ----
    float pr[4][4];
    float pmax = -1e30f;
#pragma unroll
    for (int kt = 0; kt < 4; ++kt)
#pragma unroll
      for (int r = 0; r < 4; ++r) {
        int kidx = ch * 64 + kt * 16 + 4 * lg + r;
        float s = (kidx < L) ? sa[kt][r] : -1e30f;
        pr[kt][r] = s;
        pmax = fmaxf(pmax, s);
      }
    pmax = fmaxf(pmax, __shfl_xor(pmax, 16));
    pmax = fmaxf(pmax, __shfl_xor(pmax, 32));
    if (!__all(pmax <= m_s + 8.0f)) {
      float mn = fmaxf(m_s, pmax);
      float fs = exp2f(m_s - mn);
      m_s = mn;
      float fsb[4];
#pragma unroll
      for (int r = 0; r < 4; ++r) fsb[r] = __shfl(fs, 4 * lg + r);
#pragma unroll
      for (int ct = 0; ct < 4; ++ct)
#pragma unroll
        for (int r = 0; r < 4; ++r) oa[ct][r] *= fsb[r];
      l_s *= fs;
    }
    float rs = 0.f;
#pragma unroll
    for (int kt = 0; kt < 4; ++kt)
#pragma unroll
      for (int r = 0; r < 4; ++r) {
        float e = exp2f(pr[kt][r] - m_s);
        pr[kt][r] = e;
        rs += e;
      }
    rs += __shfl_xor(rs, 16);
    rs += __shfl_xor(rs, 32);
    l_s += rs;

    // ---- store P [q][key] hi/lo (wave-private rows; no barrier needed) ----
#pragma unroll
    for (int kt = 0; kt < 4; ++kt) {
      h4 hh = {(_Float16)pr[kt][0], (_Float16)pr[kt][1], (_Float16)pr[kt][2],
               (_Float16)pr[kt][3]};
      h4 ll = {(_Float16)(pr[kt][0] - (float)hh[0]),
               (_Float16)(pr[kt][1] - (float)hh[1]),
               (_Float16)(pr[kt][2] - (float)hh[2]),
               (_Float16)(pr[kt][3] - (float)hh[3])};
      int key0 = kt * 16 + 4 * lg;
      int kgr2 = key0 >> 3, ko = key0 & 7;
      *(h4*)&Ph[fidx(w16 + lw, kgr2, ko)] = hh;
      *(h4*)&Pl[fidx(w16 + lw, kgr2, ko)] = ll;
    }

    // ---- O += P * V (V fragments from global/L2) ----
#pragma unroll
    for (int slab = 0; slab < 2; ++slab) {
      h8 pah = *(const h8*)&Ph[fidx(w16 + lw, slab * 4 + lg, 0)];
      h8 pal = *(const h8*)&Pl[fidx(w16 + lw, slab * 4 + lg, 0)];
#pragma unroll
      for (int ct = 0; ct < 4; ++ct) {
        long va = vc + ct * vctL + slab * 32;
        h8 vbh = *(const h8*)(vg + va);
        h8 vbl = *(const h8*)(vgl + va);
        oa[ct] = __builtin_amdgcn_mfma_f32_16x16x32_f16(pah, vbh, oa[ct], 0, 0, 0);
        oa[ct] = __builtin_amdgcn_mfma_f32_16x16x32_f16(pal, vbh, oa[ct], 0, 0, 0);
        oa[ct] = __builtin_amdgcn_mfma_f32_16x16x32_f16(pah, vbl, oa[ct], 0, 0, 0);
      }
    }
  }

  // ---- store O ----
  float linv[4];
#pragma unroll
  for (int r = 0; r < 4; ++r) linv[r] = 1.0f / __shfl(l_s, 4 * lg + r);
#pragma unroll
  for (int r = 0; r < 4; ++r) {
    int qi = qt * 64 + w16 + 4 * lg + r;
    if (qi < L) {
      float* op = og_ + (tokbase + qi) * 64 + lw;
#pragma unroll
      for (int ct = 0; ct < 4; ++ct) op[ct * 16] = oa[ct][r] * linv[r];
    }
  }
}

// ---------------------------------------------------------------------------
// Kernel 4: mask1 (fused) -> res conv -> mask2 -> fus conv via MFMA hi/lo.
// ---------------------------------------------------------------------------
__global__ __launch_bounds__(256) void k_fuse3(
    const float* __restrict__ x, const float* __restrict__ ex,
    const float* __restrict__ att, const float* __restrict__ m1aw,
    const float* __restrict__ m1ab, const float* __restrict__ m1bw,
    const float* __restrict__ m1bb, const _Float16* __restrict__ rwh,
    const _Float16* __restrict__ rwl, const float* __restrict__ res_b,
    const _Float16* __restrict__ fwh, const _Float16* __restrict__ fwl,
    const float* __restrict__ fus_b, const float* __restrict__ m2aw,
    const float* __restrict__ m2ab, const float* __restrict__ m2bw,
    const float* __restrict__ m2bb, float* __restrict__ out) {
  __shared__ __align__(16) _Float16 F1hS[12288];  // [64][192] swizzled
  __shared__ __align__(16) _Float16 F1lS[12288];
  float* Cb = (float*)F1hS;        // 4096 f32 overlay (16KB <= 24KB)
  _Float16* o2h = F1lS;            // out2 hi [64][64]
  _Float16* o2l = F1lS + 4096;     // out2 lo

  const int tid = threadIdx.x;
  const int posb = blockIdx.x * 64;
  const int n = posb / HW, posn = posb % HW;
  const int lane = tid & 63, w = tid >> 6;
  const int lw = lane & 15, lg = lane >> 4;
  const int w16 = w * 16;

  // ---- phase A: mask fusion 1, split + write straight to F1 LDS ----
  {
    float w1a0 = m1aw[0], w1a1 = m1aw[1], w1a2 = m1aw[2], w1a3 = m1aw[3];
    float b1a0 = m1ab[0], b1a1 = m1ab[1];
    float w1b0 = m1bw[0], w1b1 = m1bw[1], w1b2 = m1bw[2], w1b3 = m1bw[3];
    float b1b0 = m1bb[0], b1b1 = m1bb[1];
#pragma unroll 2
    for (int pp = 0; pp < 16; ++pp) {
      int pl = w * 16 + pp;
      int pos = posn + pl;
      int h = pos / CW, wcol = pos % CW;
      auto tok = [&](int S, int W) -> int {
        int wr = h / S, kx = h % S, wcq = wcol / S, ky = wcol % S;
        return kx * (S * W * W) + ky * (W * W) + wr * W + wcq;
      };
      int j0 = tok(36, 2), j1 = tok(18, 4), j2 = tok(12, 6);
      long t0 = ((long)n * HW + j0) * 64 + lane;
      long t1 = ((long)NPOS + (long)n * HW + j1) * 64 + lane;
      long t2 = (2L * NPOS + (long)n * HW + j2) * 64 + lane;
      float av0 = att[t0], av1 = att[t1], av2 = att[t2];
      float ev0 = ex[t0], ev1 = ex[t1], ev2 = ex[t2];
      float mxa = fmaxf(fmaxf(av0, av1), av2), sma = av0 + av1 + av2;
      float mxe = fmaxf(fmaxf(ev0, ev1), ev2), sme = ev0 + ev1 + ev2;
#pragma unroll
      for (int d = 1; d < 64; d <<= 1) {
        mxa = fmaxf(mxa, __shfl_xor(mxa, d));
        sma += __shfl_xor(sma, d);
        mxe = fmaxf(mxe, __shfl_xor(mxe, d));
        sme += __shfl_xor(sme, d);
      }
      float mna = sma * (1.f / 192.f), mne = sme * (1.f / 192.f);
      float ca0 = fmaf(w1a0, mxa, fmaf(w1a1, mna, b1a0));
      float ca1 = fmaf(w1a2, mxa, fmaf(w1a3, mna, b1a1));
      float cb0 = fmaf(w1b0, mxe, fmaf(w1b1, mne, b1b0));
      float cb1 = fmaf(w1b2, mxe, fmaf(w1b3, mne, b1b1));
      bool mk = (ca0 * cb0 + ca1 * cb1) > 0.f;
      float v0 = mk ? ev0 : av0;
      float v1 = mk ? ev1 : av1;
      float v2 = mk ? ev2 : av2;
      _Float16 h0 = (_Float16)v0, h1 = (_Float16)v1, h2 = (_Float16)v2;
      int c0 = lane, c1 = lane + 64, c2 = lane + 128;
      F1hS[f192(pl, c0 >> 3) + (c0 & 7)] = h0;
      F1lS[f192(pl, c0 >> 3) + (c0 & 7)] = (_Float16)(v0 - (float)h0);
      F1hS[f192(pl, c1 >> 3) + (c1 & 7)] = h1;
      F1lS[f192(pl, c1 >> 3) + (c1 & 7)] = (_Float16)(v1 - (float)h1);
      F1hS[f192(pl, c2 >> 3) + (c2 & 7)] = h2;
      F1lS[f192(pl, c2 >> 3) + (c2 & 7)] = (_Float16)(v2 - (float)h2);
    }
  }
  __syncthreads();

  // ---- A-fragments (pos rows) to registers ----
  h8 ah[6], al[6];
#pragma unroll
  for (int s = 0; s < 6; ++s) {
    ah[s] = *(const h8*)&F1hS[f192(w16 + lw, s * 4 + lg)];
    al[s] = *(const h8*)&F1lS[f192(w16 + lw, s * 4 + lg)];
  }

  // ---- res GEMM: C[pos][out], K=192 ----
  f4 acc[4];
#pragma unroll
  for (int ot = 0; ot < 4; ++ot) {
    float bb = res_b[ot * 16 + lw];
    acc[ot] = (f4){bb, bb, bb, bb};
#pragma unroll
    for (int s = 0; s < 6; ++s) {
      int wo = (ot * 16 + lw) * 192 + (s * 4 + lg) * 8;
      h8 bh = *(const h8*)(rwh + wo);
      h8 bl = *(const h8*)(rwl + wo);
      acc[ot] = __builtin_amdgcn_mfma_f32_16x16x32_f16(ah[s], bh, acc[ot], 0, 0, 0);
      acc[ot] = __builtin_amdgcn_mfma_f32_16x16x32_f16(al[s], bh, acc[ot], 0, 0, 0);
      acc[ot] = __builtin_amdgcn_mfma_f32_16x16x32_f16(ah[s], bl, acc[ot], 0, 0, 0);
    }
  }
  __syncthreads();  // all waves done reading F1 (A-frags live in regs)

  // ---- write C to Cb (qkv swizzle) ----
#pragma unroll
  for (int ot = 0; ot < 4; ++ot)
#pragma unroll
    for (int r = 0; r < 4; ++r) {
      int row = w16 + 4 * lg + r, col = ot * 16 + lw;
      Cb[(row << 6) + ((((col >> 2) ^ (row & 15))) << 2) + (col & 3)] =
          acc[ot][r];
    }
  __syncthreads();

  // ---- mask2: pool over 64 outs + 64 x-channels; quad = one position ----
  const int pos = tid >> 2, off = (tid & 3) * 16;
  float vals[16];
#pragma unroll
  for (int j = 0; j < 4; ++j) {
    int slot = (off >> 2) + j;
    f4 v = *(const f4*)&Cb[(pos << 6) + (((slot ^ (pos & 15))) << 2)];
    vals[4 * j + 0] = v[0]; vals[4 * j + 1] = v[1];
    vals[4 * j + 2] = v[2]; vals[4 * j + 3] = v[3];
  }
  float amx = vals[0], asum = vals[0];
#pragma unroll
  for (int i = 1; i < 16; ++i) {
    amx = fmaxf(amx, vals[i]);
    asum += vals[i];
  }
  amx = fmaxf(amx, __shfl_xor(amx, 1)); asum += __shfl_xor(asum, 1);
  amx = fmaxf(amx, __shfl_xor(amx, 2)); asum += __shfl_xor(asum, 2);
  float xv[16];
  const float* xp = x + ((long)n * CC + off) * HW + posn + pos;
#pragma unroll
  for (int i = 0; i < 16; ++i) xv[i] = xp[i * HW];
  float xmx = xv[0], xsum = xv[0];
#pragma unroll
  for (int i = 1; i < 16; ++i) {
    xmx = fmaxf(xmx, xv[i]);
    xsum += xv[i];
  }
  xmx = fmaxf(xmx, __shfl_xor(xmx, 1)); xsum += __shfl_xor(xsum, 1);
  xmx = fmaxf(xmx, __shfl_xor(xmx, 2)); xsum += __shfl_xor(xsum, 2);
  float rmn = asum * (1.f / 64.f), xmn = xsum * (1.f / 64.f);
  float ca0 = fmaf(m2aw[0], amx, fmaf(m2aw[1], rmn, m2ab[0]));
  float ca1 = fmaf(m2aw[2], amx, fmaf(m2aw[3], rmn, m2ab[1]));
  float cb0 = fmaf(m2bw[0], xmx, fmaf(m2bw[1], xmn, m2bb[0]));
  float cb1 = fmaf(m2bw[2], xmx, fmaf(m2bw[3], xmn, m2bb[1]));
  bool mk2 = (ca0 * cb0 + ca1 * cb1) > 0.f;

  // ---- select + hi/lo split -> out2 LDS [pos][64] ----
#pragma unroll
  for (int hf = 0; hf < 2; ++hf) {
    h8 hh, ll;
#pragma unroll
    for (int j = 0; j < 8; ++j) {
      float v = mk2 ? xv[hf * 8 + j] : vals[hf * 8 + j];
      _Float16 hx = (_Float16)v;
      hh[j] = hx;
      ll[j] = (_Float16)(v - (float)hx);
    }
    int g = (off >> 3) + hf;
    *(h8*)&o2h[fidx(pos, g, 0)] = hh;
    *(h8*)&o2l[fidx(pos, g, 0)] = ll;
  }
  __syncthreads();

  // ---- fus GEMM: C2[pos][out], K=64 ----
  h8 a2h[2], a2l[2];
#pragma unroll
  for (int s = 0; s < 2; ++s) {
    a2h[s] = *(const h8*)&o2h[fidx(w16 + lw, s * 4 + lg, 0)];
    a2l[s] = *(const h8*)&o2l[fidx(w16 + lw, s * 4 + lg, 0)];
  }
  f4 acc2[4];
#pragma unroll
  for (int ot = 0; ot < 4; ++ot) {
    float bb = fus_b[ot * 16 + lw];
    acc2[ot] = (f4){bb, bb, bb, bb};
#pragma unroll
    for (int s = 0; s < 2; ++s) {
      int wo = (ot * 16 + lw) * 64 + (s * 4 + lg) * 8;
      h8 bh = *(const h8*)(fwh + wo);
      h8 bl = *(const h8*)(fwl + wo);
      acc2[ot] = __builtin_amdgcn_mfma_f32_16x16x32_f16(a2h[s], bh, acc2[ot], 0, 0, 0);
      acc2[ot] = __builtin_amdgcn_mfma_f32_16x16x32_f16(a2l[s], bh, acc2[ot], 0, 0, 0);
      acc2[ot] = __builtin_amdgcn_mfma_f32_16x16x32_f16(a2h[s], bl, acc2[ot], 0, 0, 0);
    }
  }
  __syncthreads();  // Cb pool-reads & o2 frag-reads complete

  // ---- transpose via rotation-swizzled Cb2, then coalesced store ----
#pragma unroll
  for (int ot = 0; ot < 4; ++ot)
#pragma unroll
    for (int r = 0; r < 4; ++r) {
      int prow = w16 + 4 * lg + r, col = ot * 16 + lw;
      Cb[(prow << 6) + ((col + prow) & 63)] = acc2[ot][r];
    }
  __syncthreads();
#pragma unroll
  for (int i = 0; i < 16; ++i) {
    float v = Cb[(lane << 6) + ((w16 + i + lane) & 63)];
    out[((long)n * CC + w16 + i) * HW + posn + lane] = v;
  }
}

// ---------------------------------------------------------------------------
extern "C" void kernel_launch(void* const* d_in, const int* in_sizes, int n_in,
                              void* d_out, int out_size, void* d_ws,
                              size_t ws_size, hipStream_t stream) {
  (void)in_sizes; (void)n_in; (void)out_size;
  const float* x      = (const float*)d_in[0];
  const float* exp_w  = (const float*)d_in[1];
  const float* exp_b  = (const float*)d_in[2];
  const float* res_w  = (const float*)d_in[3];
  const float* res_b  = (const float*)d_in[4];
  const float* fus_w  = (const float*)d_in[5];
  const float* fus_b  = (const float*)d_in[6];
  const float* wq     = (const float*)d_in[7];
  const float* wk     = (const float*)d_in[8];
  const float* wv     = (const float*)d_in[9];
  const float* m1aw   = (const float*)d_in[10];
  const float* m1ab   = (const float*)d_in[11];
  const float* m1bw   = (const float*)d_in[12];
  const float* m1bb   = (const float*)d_in[13];
  const float* m2aw   = (const float*)d_in[14];
  const float* m2ab   = (const float*)d_in[15];
  const float* m2bw   = (const float*)d_in[16];
  const float* m2bb   = (const float*)d_in[17];

  const long HSZ = TOKF + HPAD;  // halves per padded half-array
  const size_t needF =
      2 * (size_t)TOKF + (6 * (size_t)HSZ + 2 * 12288 + 2 * 12288 + 2 * 4096) / 2;
  if (ws_size < needF * sizeof(float)) return;
  float* ws = (float*)d_ws;
  float* ex = ws;                              // TOKF f32
  float* ob = ex + TOKF;                       // TOKF f32
  _Float16* qh  = (_Float16*)(ob + TOKF);
  _Float16* ql  = qh + HSZ;
  _Float16* kh  = ql + HSZ;
  _Float16* kl  = kh + HSZ;
  _Float16* vth = kl + HSZ;
  _Float16* vtl = vth + HSZ;
  _Float16* wTh = vtl + HSZ;                   // 12288 halves
  _Float16* wTl = wTh + 12288;
  _Float16* rwh = wTl + 12288;                 // 12288 halves
  _Float16* rwl = rwh + 12288;
  _Float16* fwh = rwl + 12288;                 // 4096 halves
  _Float16* fwl = fwh + 4096;

  k_prep<<<1084, 256, 0, stream>>>(x, exp_w, exp_b, wq, wk, wv, res_w, fus_w,
                                   ex, wTh, wTl, rwh, rwl, fwh, fwl);
  k_qkv<<<972, 256, 0, stream>>>(ex, wTh, wTl, qh, ql, kh, kl, vth, vtl);
  k_attn<<<1152, 256, 0, stream>>>(qh, ql, kh, kl, vth, vtl, ob);
  k_fuse3<<<324, 256, 0, stream>>>(x, ex, ob, m1aw, m1ab, m1bw, m1bb, rwh,
                                   rwl, res_b, fwh, fwl, fus_b, m2aw, m2ab,
                                   m2bw, m2bb, (float*)d_out);
}

// Round 18
// 139.340 us; speedup vs baseline: 1.6404x; 1.6404x over previous
//
#include <hip/hip_runtime.h>

constexpr int CN = 4;          // batch
constexpr int CC = 64;         // channels per window
constexpr int CH = 72, CW = 72;
constexpr int HW = CH * CW;    // 5184
constexpr int NPOS = CN * HW;  // 20736 tokens per window
constexpr long TOKF = 3L * NPOS * 64;  // elems in one [3][NPOS][64] array
constexpr long HPAD = 4096;            // tail pad (halves) for OOB-safe reads

typedef _Float16 h4 __attribute__((ext_vector_type(4)));
typedef _Float16 h8 __attribute__((ext_vector_type(8)));
typedef float f4 __attribute__((ext_vector_type(4)));

// f16 [row][64] arrays: 8 granules of 8 f16 per row; swizzle granule by row&7.
__device__ __forceinline__ int fidx(int row, int g, int off) {
  return (row << 6) + ((g ^ (row & 7)) << 3) + off;
}
// f16 [row][192] arrays: 24 granules; swizzle low 3 bits of granule by row&7.
__device__ __forceinline__ int f192(int row, int g) {
  return row * 192 + (((g & 24) | ((g ^ row) & 7)) << 3);
}

// ---------------------------------------------------------------------------
// Kernel 1: expand conv (3 windows, output-split x4 for occupancy) +
// weight transpose/split, one launch.
// ---------------------------------------------------------------------------
template <int WW, int SS>
__device__ __forceinline__ void expand_body(const float* __restrict__ x,
                                            const float* __restrict__ w64,
                                            const float* __restrict__ b64,
                                            float* __restrict__ out, int pg,
                                            int og0) {
  int n = pg / HW;
  int pos = pg - n * HW;
  int h = pos / CW, wcol = pos % CW;

  float xv[64];
  const float* xp = x + (long)n * CC * HW + pos;
#pragma unroll
  for (int c = 0; c < 64; ++c) xv[c] = xp[c * HW];

  int wr = h / SS, kx = h % SS, wcq = wcol / SS, ky = wcol % SS;
  int j = kx * (SS * WW * WW) + ky * (WW * WW) + wr * WW + wcq;
  float* op = out + ((long)n * HW + j) * 64;

#pragma unroll
  for (int og = og0; og < og0 + 4; ++og) {
    float t0[4];
#pragma unroll
    for (int i = 0; i < 4; ++i) {
      int o = og * 4 + i;
      float acc = b64[o];
      const float* wp = w64 + o * 64;
#pragma unroll
      for (int cg = 0; cg < 16; ++cg) {
        float4 w4 = *(const float4*)(wp + 4 * cg);
        acc = fmaf(xv[4 * cg + 0], w4.x, acc);
        acc = fmaf(xv[4 * cg + 1], w4.y, acc);
        acc = fmaf(xv[4 * cg + 2], w4.z, acc);
        acc = fmaf(xv[4 * cg + 3], w4.w, acc);
      }
      t0[i] = acc;
    }
    *(float4*)(op + og * 4) = make_float4(t0[0], t0[1], t0[2], t0[3]);
  }
}

__global__ __launch_bounds__(256) void k_prep(
    const float* __restrict__ x, const float* __restrict__ exp_w,
    const float* __restrict__ exp_b, const float* __restrict__ wq,
    const float* __restrict__ wk, const float* __restrict__ wv,
    const float* __restrict__ res_w, const float* __restrict__ fus_w,
    float* __restrict__ ex, _Float16* __restrict__ wTh,
    _Float16* __restrict__ wTl, _Float16* __restrict__ rwh,
    _Float16* __restrict__ rwl, _Float16* __restrict__ fwh,
    _Float16* __restrict__ fwl) {
  int b = blockIdx.x;
  if (b >= 972) {  // weight transpose + hi/lo split part
    int i = (b - 972) * 256 + threadIdx.x;  // [0, 28672)
    float v;
    _Float16 *dh, *dl;
    int off;
    if (i < 12288) {
      int m = i >> 12;
      int r = i & 4095;
      int cp = r >> 6, c = r & 63;
      const float* src = (m == 0) ? wq : ((m == 1) ? wk : wv);
      v = src[c * 64 + cp];
      dh = wTh; dl = wTl; off = i;
    } else if (i < 24576) {
      off = i - 12288;
      v = res_w[off];
      dh = rwh; dl = rwl;
    } else {
      off = i - 24576;
      v = fus_w[off];
      dh = fwh; dl = fwl;
    }
    _Float16 h = (_Float16)v;
    dh[off] = h;
    dl[off] = (_Float16)(v - (float)h);
    return;
  }
  int wi = b / 324;                // window
  int b2 = b - wi * 324;
  int og0 = (b2 / 81) * 4;         // output-group quarter
  int pg = (b2 % 81) * 256 + threadIdx.x;  // [0, NPOS)
  if (wi == 0)
    expand_body<2, 36>(x, exp_w, exp_b, ex, pg, og0);
  else if (wi == 1)
    expand_body<4, 18>(x, exp_w + 4096, exp_b + 64, ex + (long)NPOS * 64, pg,
                       og0);
  else
    expand_body<6, 12>(x, exp_w + 8192, exp_b + 128, ex + 2L * NPOS * 64, pg,
                       og0);
}

// ---------------------------------------------------------------------------
// Kernel 2: q/k/v projections as MFMA fp16 hi/lo GEMM (3-term, fp32-equiv).
// ---------------------------------------------------------------------------
__global__ __launch_bounds__(256) void k_qkv(
    const float* __restrict__ ex, const _Float16* __restrict__ wTh,
    const _Float16* __restrict__ wTl, _Float16* __restrict__ qh,
    _Float16* __restrict__ ql, _Float16* __restrict__ kh,
    _Float16* __restrict__ kl, _Float16* __restrict__ vth,
    _Float16* __restrict__ vtl) {
  __shared__ __align__(16) _Float16 Wh[12288], Wl[12288];  // 192x64 swizzled
  __shared__ __align__(16) float Cb[4096];  // bounce; overlays E staging
  _Float16* Eh = (_Float16*)Cb;             // [64][64] halves
  _Float16* El = (_Float16*)Cb + 4096;

  const int tid = threadIdx.x;
  const long tok0 = (long)blockIdx.x * 64;
  const int lane = tid & 63, w = tid >> 6;
  const int lw = lane & 15, lg = lane >> 4;

  // ---- stage E (split) ----
  {
    int srow = tid >> 2, sfq = tid & 3;
#pragma unroll
    for (int p = 0; p < 4; ++p) {
      int c0 = (4 * p + sfq) * 4;
      float4 v = *(const float4*)(ex + (tok0 + srow) * 64 + c0);
      h4 hh = {(_Float16)v.x, (_Float16)v.y, (_Float16)v.z, (_Float16)v.w};
      h4 ll = {(_Float16)(v.x - (float)hh[0]), (_Float16)(v.y - (float)hh[1]),
               (_Float16)(v.z - (float)hh[2]), (_Float16)(v.w - (float)hh[3])};
      *(h4*)&Eh[fidx(srow, c0 >> 3, c0 & 7)] = hh;
      *(h4*)&El[fidx(srow, c0 >> 3, c0 & 7)] = ll;
    }
  }
  // ---- stage W (straight split copies) ----
#pragma unroll
  for (int it = 0; it < 6; ++it) {
    int idx = it * 256 + tid;  // [0,1536) h8 index
    int row = idx >> 3, gr = idx & 7;
    *(h8*)&Wh[fidx(row, gr, 0)] = *(const h8*)(wTh + idx * 8);
    *(h8*)&Wl[fidx(row, gr, 0)] = *(const h8*)(wTl + idx * 8);
  }
  __syncthreads();

  // ---- A-fragments (E rows) to registers, then free the E region ----
  h8 eh[2], el[2];
#pragma unroll
  for (int s = 0; s < 2; ++s) {
    eh[s] = *(const h8*)&Eh[fidx(w * 16 + lw, s * 4 + lg, 0)];
    el[s] = *(const h8*)&El[fidx(w * 16 + lw, s * 4 + lg, 0)];
  }
  __syncthreads();

  const float SC = 0.125f * 1.4426950408889634f;
#pragma unroll 1
  for (int p = 0; p < 3; ++p) {
#pragma unroll
    for (int ot = 0; ot < 4; ++ot) {
      f4 acc = (f4){0.f, 0.f, 0.f, 0.f};
#pragma unroll
      for (int s = 0; s < 2; ++s) {
        h8 bh = *(const h8*)&Wh[fidx(p * 64 + ot * 16 + lw, s * 4 + lg, 0)];
        h8 bl = *(const h8*)&Wl[fidx(p * 64 + ot * 16 + lw, s * 4 + lg, 0)];
        acc = __builtin_amdgcn_mfma_f32_16x16x32_f16(eh[s], bh, acc, 0, 0, 0);
        acc = __builtin_amdgcn_mfma_f32_16x16x32_f16(el[s], bh, acc, 0, 0, 0);
        acc = __builtin_amdgcn_mfma_f32_16x16x32_f16(eh[s], bl, acc, 0, 0, 0);
      }
#pragma unroll
      for (int r = 0; r < 4; ++r) {
        int row = w * 16 + 4 * lg + r;
        int col = ot * 16 + lw;
        Cb[(row << 6) + ((((col >> 2) ^ (row & 15))) << 2) + (col & 3)] =
            acc[r];
      }
    }
    __syncthreads();

    if (p < 2) {
      int tokl = tid >> 2, off = (tid & 3) * 16;
      float vals[16];
#pragma unroll
      for (int j = 0; j < 4; ++j) {
        int slot = (off >> 2) + j;
        f4 v = *(const f4*)&Cb[(tokl << 6) + (((slot ^ (tokl & 15))) << 2)];
        vals[4 * j + 0] = v[0]; vals[4 * j + 1] = v[1];
        vals[4 * j + 2] = v[2]; vals[4 * j + 3] = v[3];
      }
      float sc = (p == 0) ? SC : 1.0f;
      _Float16* dh = (p == 0 ? qh : kh) + (tok0 + tokl) * 64 + off;
      _Float16* dl = (p == 0 ? ql : kl) + (tok0 + tokl) * 64 + off;
      h8 hh0, hh1, ll0, ll1;
#pragma unroll
      for (int j = 0; j < 8; ++j) {
        float x0 = vals[j] * sc;
        _Float16 h = (_Float16)x0;
        hh0[j] = h;
        ll0[j] = (_Float16)(x0 - (float)h);
        float x1 = vals[8 + j] * sc;
        _Float16 h1 = (_Float16)x1;
        hh1[j] = h1;
        ll1[j] = (_Float16)(x1 - (float)h1);
      }
      *(h8*)dh = hh0; *(h8*)(dh + 8) = hh1;
      *(h8*)dl = ll0; *(h8*)(dl + 8) = ll1;
    } else {
      int ch0 = (tid & 15) * 4, tokl0 = (tid >> 4) * 4;
      float tv[4][4];
#pragma unroll
      for (int r = 0; r < 4; ++r) {
        int row = tokl0 + r;
        int slot = (ch0 >> 2) ^ (row & 15);
        f4 v = *(const f4*)&Cb[(row << 6) + (slot << 2)];
        tv[r][0] = v[0]; tv[r][1] = v[1]; tv[r][2] = v[2]; tv[r][3] = v[3];
      }
      long tokg = tok0 + tokl0;
      int wi = (int)(tokg / NPOS);
      long tl = tokg - (long)wi * NPOS;
      int L = (wi == 0) ? 1296 : ((wi == 1) ? 324 : 144);
      int g = (int)(tl / L);
      int key0 = (int)(tl - (long)g * L);
      long base = (long)wi * NPOS * 64 + (long)g * 64 * L + key0;
#pragma unroll
      for (int i = 0; i < 4; ++i) {
        h4 hh, ll;
#pragma unroll
        for (int r = 0; r < 4; ++r) {
          _Float16 h = (_Float16)tv[r][i];
          hh[r] = h;
          ll[r] = (_Float16)(tv[r][i] - (float)h);
        }
        *(h4*)&vth[base + (long)(ch0 + i) * L] = hh;
        *(h4*)&vtl[base + (long)(ch0 + i) * L] = ll;
      }
    }
    __syncthreads();
  }
}

// ---------------------------------------------------------------------------
// Kernel 3: merged MFMA attention (r12/r16 structure: 256 thr, 16q/wave,
// XCD-pin, defer-max, LDS-staged K/V with register double-buffer).
// This structure is the measured floor (~62us); r13/r17 alternatives failed.
// ---------------------------------------------------------------------------
__global__ __launch_bounds__(256) void k_attn(
    const _Float16* __restrict__ qg, const _Float16* __restrict__ qgl,
    const _Float16* __restrict__ kg, const _Float16* __restrict__ kgl,
    const _Float16* __restrict__ vg, const _Float16* __restrict__ vgl,
    float* __restrict__ og_) {
  __shared__ __align__(16) _Float16 Kh[4096], Kl[4096];
  __shared__ __align__(16) _Float16 Vh[4096], Vl[4096];  // V^T [ch][key]
  __shared__ __align__(16) _Float16 Ph[4096], Pl[4096];  // P  [q][key]

  const int tid = threadIdx.x;
  int b = blockIdx.x;
  int L, g, qt, NCH;
  long tokbase, vbase;
  if (b < 336) {          // w1: 16 groups x 21 tiles; g = b mod 16 (XCD-pin)
    L = 1296; NCH = 21; g = b & 15; qt = b >> 4;
    tokbase = (long)g * 1296;
    vbase = (long)g * 1296 * 64;
  } else if (b < 720) {   // w2: 64 groups x 6 tiles; g = t mod 64
    int t = b - 336;
    L = 324; NCH = 6; g = t & 63; qt = t >> 6;
    tokbase = (long)NPOS + (long)g * 324;
    vbase = (long)NPOS * 64 + (long)g * 324 * 64;
  } else {                // w3: 144 groups x 3 tiles; g = t mod 144
    int t = b - 720;
    L = 144; NCH = 3; g = t % 144; qt = t / 144;
    tokbase = 2L * NPOS + (long)g * 144;
    vbase = 2L * NPOS * 64 + (long)g * 144 * 64;
  }

  const int lane = tid & 63, w = tid >> 6;
  const int lw = lane & 15, lg = lane >> 4;
  const int w16 = w * 16;

  // ---- Q fragments straight to registers (loop-invariant; pad-safe) ----
  h8 qfh[2], qfl[2];
  {
    long qb = (tokbase + (long)qt * 64 + w16 + lw) * 64;
#pragma unroll
    for (int s = 0; s < 2; ++s) {
      qfh[s] = *(const h8*)(qg + qb + (s * 4 + lg) * 8);
      qfl[s] = *(const h8*)(qgl + qb + (s * 4 + lg) * 8);
    }
  }

  float m_s = -1e30f, l_s = 0.f;
  f4 oa[4];
#pragma unroll
  for (int i = 0; i < 4; ++i) oa[i] = (f4){0.f, 0.f, 0.f, 0.f};

  const int krow = tid >> 3, kgr = tid & 7;
  const long ksA = (tokbase + krow) * 64 + kgr * 8;
  const long vsA = vbase + (long)krow * L + kgr * 8;
  const long v32 = (long)32 * L;

  h8 rk0, rk1, rl0, rl1, rv0, rv1, rw0, rw1;
  auto loadKV = [&](int chn) {
    long ko = ksA + ((long)chn << 12);
    long vo = vsA + chn * 64;
    rk0 = *(const h8*)(kg + ko);
    rl0 = *(const h8*)(kgl + ko);
    rv0 = *(const h8*)(vg + vo);
    rw0 = *(const h8*)(vgl + vo);
    rk1 = *(const h8*)(kg + ko + 2048);
    rl1 = *(const h8*)(kgl + ko + 2048);
    rv1 = *(const h8*)(vg + vo + v32);
    rw1 = *(const h8*)(vgl + vo + v32);
  };
  loadKV(0);

  for (int ch = 0; ch < NCH; ++ch) {
    __syncthreads();
    {
      *(h8*)&Kh[fidx(krow, kgr, 0)] = rk0;
      *(h8*)&Kl[fidx(krow, kgr, 0)] = rl0;
      *(h8*)&Vh[fidx(krow, kgr, 0)] = rv0;
      *(h8*)&Vl[fidx(krow, kgr, 0)] = rw0;
      *(h8*)&Kh[fidx(32 + krow, kgr, 0)] = rk1;
      *(h8*)&Kl[fidx(32 + krow, kgr, 0)] = rl1;
      *(h8*)&Vh[fidx(32 + krow, kgr, 0)] = rv1;
      *(h8*)&Vl[fidx(32 + krow, kgr, 0)] = rw1;
    }
    __syncthreads();
    if (ch + 1 < NCH) loadKV(ch + 1);

    // ---- S^T = K * Q^T ----
    f4 sa[4];
#pragma unroll
    for (int kt = 0; kt < 4; ++kt) sa[kt] = (f4){0.f, 0.f, 0.f, 0.f};
#pragma unroll
    for (int slab = 0; slab < 2; ++slab) {
      h8 qbh = qfh[slab];
      h8 qbl = qfl[slab];
#pragma unroll
      for (int kt = 0; kt < 4; ++kt) {
        h8 ah = *(const h8*)&Kh[fidx(kt * 16 + lw, slab * 4 + lg, 0)];
        h8 al = *(const h8*)&Kl[fidx(kt * 16 + lw, slab * 4 + lg, 0)];
        sa[kt] = __builtin_amdgcn_mfma_f32_16x16x32_f16(ah, qbh, sa[kt], 0, 0, 0);
        sa[kt] = __builtin_amdgcn_mfma_f32_16x16x32_f16(al, qbh, sa[kt], 0, 0, 0);
        sa[kt] = __builtin_amdgcn_mfma_f32_16x16x32_f16(ah, qbl, sa[kt], 0, 0, 0);
      }
    }

    // ---- online softmax (exp2 domain, defer-max THR=8) ----
    float pr[4][4];
    float pmax = -1e30f;
#pragma unroll
    for (int kt = 0; kt < 4; ++kt)
#pragma unroll
      for (int r = 0; r < 4; ++r) {
        int kidx = ch * 64 + kt * 16 + 4 * lg + r;
        float s = (kidx < L) ? sa[kt][r] : -1e30f;
        pr[kt][r] = s;
        pmax = fmaxf(pmax, s);
      }
    pmax = fmaxf(pmax, __shfl_xor(pmax, 16));
    pmax = fmaxf(pmax, __shfl_xor(pmax, 32));
    if (!__all(pmax <= m_s + 8.0f)) {
      float mn = fmaxf(m_s, pmax);
      float fs = exp2f(m_s - mn);
      m_s = mn;
      float fsb[4];
#pragma unroll
      for (int r = 0; r < 4; ++r) fsb[r] = __shfl(fs, 4 * lg + r);
#pragma unroll
      for (int ct = 0; ct < 4; ++ct)
#pragma unroll
        for (int r = 0; r < 4; ++r) oa[ct][r] *= fsb[r];
      l_s *= fs;
    }
    float rs = 0.f;
#pragma unroll
    for (int kt = 0; kt < 4; ++kt)
#pragma unroll
      for (int r = 0; r < 4; ++r) {
        float e = exp2f(pr[kt][r] - m_s);
        pr[kt][r] = e;
        rs += e;
      }
    rs += __shfl_xor(rs, 16);
    rs += __shfl_xor(rs, 32);
    l_s += rs;

    // ---- store P [q][key] hi/lo (wave-private rows) ----
#pragma unroll
    for (int kt = 0; kt < 4; ++kt) {
      h4 hh = {(_Float16)pr[kt][0], (_Float16)pr[kt][1], (_Float16)pr[kt][2],
               (_Float16)pr[kt][3]};
      h4 ll = {(_Float16)(pr[kt][0] - (float)hh[0]),
               (_Float16)(pr[kt][1] - (float)hh[1]),
               (_Float16)(pr[kt][2] - (float)hh[2]),
               (_Float16)(pr[kt][3] - (float)hh[3])};
      int key0 = kt * 16 + 4 * lg;
      int kgr2 = key0 >> 3, ko = key0 & 7;
      *(h4*)&Ph[fidx(w16 + lw, kgr2, ko)] = hh;
      *(h4*)&Pl[fidx(w16 + lw, kgr2, ko)] = ll;
    }

    // ---- O += P * V ----
#pragma unroll
    for (int slab = 0; slab < 2; ++slab) {
      h8 pah = *(const h8*)&Ph[fidx(w16 + lw, slab * 4 + lg, 0)];
      h8 pal = *(const h8*)&Pl[fidx(w16 + lw, slab * 4 + lg, 0)];
#pragma unroll
      for (int ct = 0; ct < 4; ++ct) {
        h8 vbh = *(const h8*)&Vh[fidx(ct * 16 + lw, slab * 4 + lg, 0)];
        h8 vbl = *(const h8*)&Vl[fidx(ct * 16 + lw, slab * 4 + lg, 0)];
        oa[ct] = __builtin_amdgcn_mfma_f32_16x16x32_f16(pah, vbh, oa[ct], 0, 0, 0);
        oa[ct] = __builtin_amdgcn_mfma_f32_16x16x32_f16(pal, vbh, oa[ct], 0, 0, 0);
        oa[ct] = __builtin_amdgcn_mfma_f32_16x16x32_f16(pah, vbl, oa[ct], 0, 0, 0);
      }
    }
  }

  // ---- store O ----
  float linv[4];
#pragma unroll
  for (int r = 0; r < 4; ++r) linv[r] = 1.0f / __shfl(l_s, 4 * lg + r);
#pragma unroll
  for (int r = 0; r < 4; ++r) {
    int qi = qt * 64 + w16 + 4 * lg + r;
    if (qi < L) {
      float* op = og_ + (tokbase + qi) * 64 + lw;
#pragma unroll
      for (int ct = 0; ct < 4; ++ct) op[ct * 16] = oa[ct][r] * linv[r];
    }
  }
}

// ---------------------------------------------------------------------------
// Kernel 4: mask1 (fused) -> res conv -> mask2 -> fus conv via MFMA hi/lo.
// ---------------------------------------------------------------------------
__global__ __launch_bounds__(256) void k_fuse3(
    const float* __restrict__ x, const float* __restrict__ ex,
    const float* __restrict__ att, const float* __restrict__ m1aw,
    const float* __restrict__ m1ab, const float* __restrict__ m1bw,
    const float* __restrict__ m1bb, const _Float16* __restrict__ rwh,
    const _Float16* __restrict__ rwl, const float* __restrict__ res_b,
    const _Float16* __restrict__ fwh, const _Float16* __restrict__ fwl,
    const float* __restrict__ fus_b, const float* __restrict__ m2aw,
    const float* __restrict__ m2ab, const float* __restrict__ m2bw,
    const float* __restrict__ m2bb, float* __restrict__ out) {
  __shared__ __align__(16) _Float16 F1hS[12288];  // [64][192] swizzled
  __shared__ __align__(16) _Float16 F1lS[12288];
  float* Cb = (float*)F1hS;        // 4096 f32 overlay (16KB <= 24KB)
  _Float16* o2h = F1lS;            // out2 hi [64][64]
  _Float16* o2l = F1lS + 4096;     // out2 lo

  const int tid = threadIdx.x;
  const int posb = blockIdx.x * 64;
  const int n = posb / HW, posn = posb % HW;
  const int lane = tid & 63, w = tid >> 6;
  const int lw = lane & 15, lg = lane >> 4;
  const int w16 = w * 16;

  // ---- phase A: mask fusion 1, split + write straight to F1 LDS ----
  {
    float w1a0 = m1aw[0], w1a1 = m1aw[1], w1a2 = m1aw[2], w1a3 = m1aw[3];
    float b1a0 = m1ab[0], b1a1 = m1ab[1];
    float w1b0 = m1bw[0], w1b1 = m1bw[1], w1b2 = m1bw[2], w1b3 = m1bw[3];
    float b1b0 = m1bb[0], b1b1 = m1bb[1];
#pragma unroll 2
    for (int pp = 0; pp < 16; ++pp) {
      int pl = w * 16 + pp;
      int pos = posn + pl;
      int h = pos / CW, wcol = pos % CW;
      auto tok = [&](int S, int W) -> int {
        int wr = h / S, kx = h % S, wcq = wcol / S, ky = wcol % S;
        return kx * (S * W * W) + ky * (W * W) + wr * W + wcq;
      };
      int j0 = tok(36, 2), j1 = tok(18, 4), j2 = tok(12, 6);
      long t0 = ((long)n * HW + j0) * 64 + lane;
      long t1 = ((long)NPOS + (long)n * HW + j1) * 64 + lane;
      long t2 = (2L * NPOS + (long)n * HW + j2) * 64 + lane;
      float av0 = att[t0], av1 = att[t1], av2 = att[t2];
      float ev0 = ex[t0], ev1 = ex[t1], ev2 = ex[t2];
      float mxa = fmaxf(fmaxf(av0, av1), av2), sma = av0 + av1 + av2;
      float mxe = fmaxf(fmaxf(ev0, ev1), ev2), sme = ev0 + ev1 + ev2;
#pragma unroll
      for (int d = 1; d < 64; d <<= 1) {
        mxa = fmaxf(mxa, __shfl_xor(mxa, d));
        sma += __shfl_xor(sma, d);
        mxe = fmaxf(mxe, __shfl_xor(mxe, d));
        sme += __shfl_xor(sme, d);
      }
      float mna = sma * (1.f / 192.f), mne = sme * (1.f / 192.f);
      float ca0 = fmaf(w1a0, mxa, fmaf(w1a1, mna, b1a0));
      float ca1 = fmaf(w1a2, mxa, fmaf(w1a3, mna, b1a1));
      float cb0 = fmaf(w1b0, mxe, fmaf(w1b1, mne, b1b0));
      float cb1 = fmaf(w1b2, mxe, fmaf(w1b3, mne, b1b1));
      bool mk = (ca0 * cb0 + ca1 * cb1) > 0.f;
      float v0 = mk ? ev0 : av0;
      float v1 = mk ? ev1 : av1;
      float v2 = mk ? ev2 : av2;
      _Float16 h0 = (_Float16)v0, h1 = (_Float16)v1, h2 = (_Float16)v2;
      int c0 = lane, c1 = lane + 64, c2 = lane + 128;
      F1hS[f192(pl, c0 >> 3) + (c0 & 7)] = h0;
      F1lS[f192(pl, c0 >> 3) + (c0 & 7)] = (_Float16)(v0 - (float)h0);
      F1hS[f192(pl, c1 >> 3) + (c1 & 7)] = h1;
      F1lS[f192(pl, c1 >> 3) + (c1 & 7)] = (_Float16)(v1 - (float)h1);
      F1hS[f192(pl, c2 >> 3) + (c2 & 7)] = h2;
      F1lS[f192(pl, c2 >> 3) + (c2 & 7)] = (_Float16)(v2 - (float)h2);
    }
  }
  __syncthreads();

  // ---- A-fragments (pos rows) to registers ----
  h8 ah[6], al[6];
#pragma unroll
  for (int s = 0; s < 6; ++s) {
    ah[s] = *(const h8*)&F1hS[f192(w16 + lw, s * 4 + lg)];
    al[s] = *(const h8*)&F1lS[f192(w16 + lw, s * 4 + lg)];
  }

  // ---- res GEMM: C[pos][out], K=192 ----
  f4 acc[4];
#pragma unroll
  for (int ot = 0; ot < 4; ++ot) {
    float bb = res_b[ot * 16 + lw];
    acc[ot] = (f4){bb, bb, bb, bb};
#pragma unroll
    for (int s = 0; s < 6; ++s) {
      int wo = (ot * 16 + lw) * 192 + (s * 4 + lg) * 8;
      h8 bh = *(const h8*)(rwh + wo);
      h8 bl = *(const h8*)(rwl + wo);
      acc[ot] = __builtin_amdgcn_mfma_f32_16x16x32_f16(ah[s], bh, acc[ot], 0, 0, 0);
      acc[ot] = __builtin_amdgcn_mfma_f32_16x16x32_f16(al[s], bh, acc[ot], 0, 0, 0);
      acc[ot] = __builtin_amdgcn_mfma_f32_16x16x32_f16(ah[s], bl, acc[ot], 0, 0, 0);
    }
  }
  __syncthreads();  // all waves done reading F1 (A-frags live in regs)

  // ---- write C to Cb (qkv swizzle) ----
#pragma unroll
  for (int ot = 0; ot < 4; ++ot)
#pragma unroll
    for (int r = 0; r < 4; ++r) {
      int row = w16 + 4 * lg + r, col = ot * 16 + lw;
      Cb[(row << 6) + ((((col >> 2) ^ (row & 15))) << 2) + (col & 3)] =
          acc[ot][r];
    }
  __syncthreads();

  // ---- mask2: pool over 64 outs + 64 x-channels; quad = one position ----
  const int pos = tid >> 2, off = (tid & 3) * 16;
  float vals[16];
#pragma unroll
  for (int j = 0; j < 4; ++j) {
    int slot = (off >> 2) + j;
    f4 v = *(const f4*)&Cb[(pos << 6) + (((slot ^ (pos & 15))) << 2)];
    vals[4 * j + 0] = v[0]; vals[4 * j + 1] = v[1];
    vals[4 * j + 2] = v[2]; vals[4 * j + 3] = v[3];
  }
  float amx = vals[0], asum = vals[0];
#pragma unroll
  for (int i = 1; i < 16; ++i) {
    amx = fmaxf(amx, vals[i]);
    asum += vals[i];
  }
  amx = fmaxf(amx, __shfl_xor(amx, 1)); asum += __shfl_xor(asum, 1);
  amx = fmaxf(amx, __shfl_xor(amx, 2)); asum += __shfl_xor(asum, 2);
  float xv[16];
  const float* xp = x + ((long)n * CC + off) * HW + posn + pos;
#pragma unroll
  for (int i = 0; i < 16; ++i) xv[i] = xp[i * HW];
  float xmx = xv[0], xsum = xv[0];
#pragma unroll
  for (int i = 1; i < 16; ++i) {
    xmx = fmaxf(xmx, xv[i]);
    xsum += xv[i];
  }
  xmx = fmaxf(xmx, __shfl_xor(xmx, 1)); xsum += __shfl_xor(xsum, 1);
  xmx = fmaxf(xmx, __shfl_xor(xmx, 2)); xsum += __shfl_xor(xsum, 2);
  float rmn = asum * (1.f / 64.f), xmn = xsum * (1.f / 64.f);
  float ca0 = fmaf(m2aw[0], amx, fmaf(m2aw[1], rmn, m2ab[0]));
  float ca1 = fmaf(m2aw[2], amx, fmaf(m2aw[3], rmn, m2ab[1]));
  float cb0 = fmaf(m2bw[0], xmx, fmaf(m2bw[1], xmn, m2bb[0]));
  float cb1 = fmaf(m2bw[2], xmx, fmaf(m2bw[3], xmn, m2bb[1]));
  bool mk2 = (ca0 * cb0 + ca1 * cb1) > 0.f;

  // ---- select + hi/lo split -> out2 LDS [pos][64] ----
#pragma unroll
  for (int hf = 0; hf < 2; ++hf) {
    h8 hh, ll;
#pragma unroll
    for (int j = 0; j < 8; ++j) {
      float v = mk2 ? xv[hf * 8 + j] : vals[hf * 8 + j];
      _Float16 hx = (_Float16)v;
      hh[j] = hx;
      ll[j] = (_Float16)(v - (float)hx);
    }
    int g = (off >> 3) + hf;
    *(h8*)&o2h[fidx(pos, g, 0)] = hh;
    *(h8*)&o2l[fidx(pos, g, 0)] = ll;
  }
  __syncthreads();

  // ---- fus GEMM: C2[pos][out], K=64 ----
  h8 a2h[2], a2l[2];
#pragma unroll
  for (int s = 0; s < 2; ++s) {
    a2h[s] = *(const h8*)&o2h[fidx(w16 + lw, s * 4 + lg, 0)];
    a2l[s] = *(const h8*)&o2l[fidx(w16 + lw, s * 4 + lg, 0)];
  }
  f4 acc2[4];
#pragma unroll
  for (int ot = 0; ot < 4; ++ot) {
    float bb = fus_b[ot * 16 + lw];
    acc2[ot] = (f4){bb, bb, bb, bb};
#pragma unroll
    for (int s = 0; s < 2; ++s) {
      int wo = (ot * 16 + lw) * 64 + (s * 4 + lg) * 8;
      h8 bh = *(const h8*)(fwh + wo);
      h8 bl = *(const h8*)(fwl + wo);
      acc2[ot] = __builtin_amdgcn_mfma_f32_16x16x32_f16(a2h[s], bh, acc2[ot], 0, 0, 0);
      acc2[ot] = __builtin_amdgcn_mfma_f32_16x16x32_f16(a2l[s], bh, acc2[ot], 0, 0, 0);
      acc2[ot] = __builtin_amdgcn_mfma_f32_16x16x32_f16(a2h[s], bl, acc2[ot], 0, 0, 0);
    }
  }
  __syncthreads();  // Cb pool-reads & o2 frag-reads complete

  // ---- transpose via rotation-swizzled Cb2, then coalesced store ----
#pragma unroll
  for (int ot = 0; ot < 4; ++ot)
#pragma unroll
    for (int r = 0; r < 4; ++r) {
      int prow = w16 + 4 * lg + r, col = ot * 16 + lw;
      Cb[(prow << 6) + ((col + prow) & 63)] = acc2[ot][r];
    }
  __syncthreads();
#pragma unroll
  for (int i = 0; i < 16; ++i) {
    float v = Cb[(lane << 6) + ((w16 + i + lane) & 63)];
    out[((long)n * CC + w16 + i) * HW + posn + lane] = v;
  }
}

// ---------------------------------------------------------------------------
extern "C" void kernel_launch(void* const* d_in, const int* in_sizes, int n_in,
                              void* d_out, int out_size, void* d_ws,
                              size_t ws_size, hipStream_t stream) {
  (void)in_sizes; (void)n_in; (void)out_size;
  const float* x      = (const float*)d_in[0];
  const float* exp_w  = (const float*)d_in[1];
  const float* exp_b  = (const float*)d_in[2];
  const float* res_w  = (const float*)d_in[3];
  const float* res_b  = (const float*)d_in[4];
  const float* fus_w  = (const float*)d_in[5];
  const float* fus_b  = (const float*)d_in[6];
  const float* wq     = (const float*)d_in[7];
  const float* wk     = (const float*)d_in[8];
  const float* wv     = (const float*)d_in[9];
  const float* m1aw   = (const float*)d_in[10];
  const float* m1ab   = (const float*)d_in[11];
  const float* m1bw   = (const float*)d_in[12];
  const float* m1bb   = (const float*)d_in[13];
  const float* m2aw   = (const float*)d_in[14];
  const float* m2ab   = (const float*)d_in[15];
  const float* m2bw   = (const float*)d_in[16];
  const float* m2bb   = (const float*)d_in[17];

  const long HSZ = TOKF + HPAD;  // halves per padded half-array
  const size_t needF =
      2 * (size_t)TOKF + (6 * (size_t)HSZ + 2 * 12288 + 2 * 12288 + 2 * 4096) / 2;
  if (ws_size < needF * sizeof(float)) return;
  float* ws = (float*)d_ws;
  float* ex = ws;                              // TOKF f32
  float* ob = ex + TOKF;                       // TOKF f32
  _Float16* qh  = (_Float16*)(ob + TOKF);
  _Float16* ql  = qh + HSZ;
  _Float16* kh  = ql + HSZ;
  _Float16* kl  = kh + HSZ;
  _Float16* vth = kl + HSZ;
  _Float16* vtl = vth + HSZ;
  _Float16* wTh = vtl + HSZ;                   // 12288 halves
  _Float16* wTl = wTh + 12288;
  _Float16* rwh = wTl + 12288;                 // 12288 halves
  _Float16* rwl = rwh + 12288;
  _Float16* fwh = rwl + 12288;                 // 4096 halves
  _Float16* fwl = fwh + 4096;

  k_prep<<<1084, 256, 0, stream>>>(x, exp_w, exp_b, wq, wk, wv, res_w, fus_w,
                                   ex, wTh, wTl, rwh, rwl, fwh, fwl);
  k_qkv<<<972, 256, 0, stream>>>(ex, wTh, wTl, qh, ql, kh, kl, vth, vtl);
  k_attn<<<1152, 256, 0, stream>>>(qh, ql, kh, kl, vth, vtl, ob);
  k_fuse3<<<324, 256, 0, stream>>>(x, ex, ob, m1aw, m1ab, m1bw, m1bb, rwh,
                                   rwl, res_b, fwh, fwl, fus_b, m2aw, m2ab,
                                   m2bw, m2bb, (float*)d_out);
}